// Round 3
// baseline (1722.037 us; speedup 1.0000x reference)
//
#include <hip/hip_runtime.h>

typedef __bf16 bf16x8 __attribute__((ext_vector_type(8)));
typedef __bf16 bf16x4 __attribute__((ext_vector_type(4)));
typedef float  f32x4  __attribute__((ext_vector_type(4)));

#define MFMA16 __builtin_amdgcn_mfma_f32_16x16x32_bf16
#define GLL16(g, l) __builtin_amdgcn_global_load_lds( \
    (const __attribute__((address_space(1))) void*)(g), \
    (__attribute__((address_space(3))) void*)(l), 16, 0, 0)

__device__ __forceinline__ float fsig(float x)  { return 1.f / (1.f + __expf(-x)); }
__device__ __forceinline__ float ftanh(float x) { return 1.f - 2.f / (__expf(2.f * x) + 1.f); }

// B=512, T=20, D=1024, H=1024, 4H=4096. Layer 0 of the LSTM is dead code.

// ---- sort batch rows by dlen descending (stable, deterministic) ----
__global__ __launch_bounds__(512) void sort_rows(
    const int* __restrict__ dlen, int* __restrict__ perm,
    int* __restrict__ dl_s, int* __restrict__ n_act)
{
    __shared__ int sdl[512];
    const int b = threadIdx.x;
    const int dl = dlen[b];
    sdl[b] = dl;
    __syncthreads();
    int pos = 0;
    for (int j = 0; j < 512; ++j) {
        const int dj = sdl[j];
        pos += (dj > dl) || (dj == dl && j < b);
    }
    perm[pos] = b;
    dl_s[pos] = dl;
    if (b < 20) {
        int cnt = 0;
        for (int j = 0; j < 512; ++j) cnt += (sdl[j] > b);
        n_act[b] = cnt;           // #rows active at step t (always n_act[0]==512)
    }
}

// ---- convert layer-1 weights + W1 to bf16; bsum_p = permuted (b_ih+b_hh) ----
// bsum_p[c] is for Xg column layout c = ch*4 + gate.
__global__ __launch_bounds__(256) void convert_weights(
    const float* __restrict__ Wih, const float* __restrict__ Whh,
    const float* __restrict__ W1,  const float* __restrict__ bih,
    const float* __restrict__ bhh,
    __bf16* __restrict__ Wih1, __bf16* __restrict__ Whh1,
    __bf16* __restrict__ W1b,  float* __restrict__ bsum_p)
{
    const size_t L1 = 4096UL * 1024UL;
    size_t i = (size_t)blockIdx.x * 256 + threadIdx.x;   // 0 .. 1048575
    float4 a = *(const float4*)(Wih + L1 + i * 4);
    float4 b = *(const float4*)(Whh + L1 + i * 4);
    bf16x4 av = { (__bf16)a.x, (__bf16)a.y, (__bf16)a.z, (__bf16)a.w };
    bf16x4 bv = { (__bf16)b.x, (__bf16)b.y, (__bf16)b.z, (__bf16)b.w };
    *(bf16x4*)(Wih1 + i * 4) = av;
    *(bf16x4*)(Whh1 + i * 4) = bv;
    W1b[i] = (__bf16)W1[i];
    if (i < 4096) {
        const int m = ((int)i & 3) * 1024 + ((int)i >> 2);  // gate*1024 + ch
        bsum_p[i] = bih[4096 + m] + bhh[4096 + m];
    }
}

// ---- gather x in SORTED row order: xbf[t*512+sb] = [rel_emb | ent_emb] ----
__global__ __launch_bounds__(256) void gather_x(
    const int* __restrict__ ent, const int* __restrict__ rel,
    const float* __restrict__ ent_emb, const float* __restrict__ rel_emb,
    const int* __restrict__ perm, __bf16* __restrict__ xbf)
{
    int bid = blockIdx.x;              // sb*20 + t
    int sb = bid / 20, t = bid - sb * 20;
    int bo = perm[sb];
    int tid = threadIdx.x;
    int col = (tid & 127) * 4;
    const float* src = (tid < 128)
        ? (rel_emb + (size_t)rel[bo * 20 + t] * 512 + col)
        : (ent_emb + (size_t)ent[bo * 20 + t] * 512 + col);
    float4 v = *(const float4*)src;
    bf16x4 o = { (__bf16)v.x, (__bf16)v.y, (__bf16)v.z, (__bf16)v.w };
    int outcol = (tid < 128) ? col : (512 + col);
    *(bf16x4*)(xbf + (size_t)(t * 512 + sb) * 1024 + outcol) = o;
}

// ---- bf16 MFMA GEMM: C[M,N] = A[M,K] @ B[N,K]^T + bias, opt ReLU ----
// PERM: B-row for output col c is (c&3)*1024 + (c>>2)  (gate-interleaved Xg cols)
// SKIP: early-exit blocks whose 128-row slab is entirely dead (rows sorted per t)
template<bool RELU, bool PERM, bool SKIP>
__global__ __launch_bounds__(256) void gemm_bias(
    const __bf16* __restrict__ A, const __bf16* __restrict__ B,
    const float* __restrict__ bias, __bf16* __restrict__ C,
    int M, int N, int K, const int* __restrict__ nact)
{
    const int m0 = blockIdx.x * 128, n0 = blockIdx.y * 128;
    if (SKIP) {
        if ((m0 & 511) >= nact[m0 >> 9]) return;
    }
    __shared__ __bf16 As[128 * 64];
    __shared__ __bf16 Bs[128 * 64];
    const int tid = threadIdx.x;
    const int w = tid >> 6, lane = tid & 63;
    const int wr = (w >> 1) * 64, wc = (w & 1) * 64;
    const int srow = lane >> 3;
    const int scol = (lane & 7) * 8;

    f32x4 acc[4][4] = {};

    for (int k0 = 0; k0 < K; k0 += 64) {
#pragma unroll
        for (int j = 0; j < 4; ++j) {
            const int r = (w * 4 + j) * 8 + srow;        // 0..127
            GLL16(A + (size_t)(m0 + r) * K + k0 + scol, As + (w * 4 + j) * 512);
            const int rr = n0 + r;
            const int R = PERM ? ((rr & 3) * 1024 + (rr >> 2)) : rr;
            GLL16(B + (size_t)R * K + k0 + scol, Bs + (w * 4 + j) * 512);
        }
        __syncthreads();
#pragma unroll
        for (int ks = 0; ks < 2; ++ks) {
            const int ko = ks * 32 + (lane >> 4) * 8;
            bf16x8 af[4], bb[4];
#pragma unroll
            for (int i = 0; i < 4; ++i)
                af[i] = *(const bf16x8*)&As[(wr + i * 16 + (lane & 15)) * 64 + ko];
#pragma unroll
            for (int j = 0; j < 4; ++j)
                bb[j] = *(const bf16x8*)&Bs[(wc + j * 16 + (lane & 15)) * 64 + ko];
#pragma unroll
            for (int i = 0; i < 4; ++i)
#pragma unroll
                for (int j = 0; j < 4; ++j)
                    acc[i][j] = MFMA16(af[i], bb[j], acc[i][j], 0, 0, 0);
        }
        __syncthreads();
    }
    const int rbase = m0 + wr + (lane >> 4) * 4;
    const int cbase = n0 + wc + (lane & 15);
#pragma unroll
    for (int j = 0; j < 4; ++j) {
        const int col = cbase + j * 16;
        const float bv = bias[col];
#pragma unroll
        for (int i = 0; i < 4; ++i)
#pragma unroll
            for (int r = 0; r < 4; ++r) {
                float v = acc[i][j][r] + bv;
                if (RELU) v = fmaxf(v, 0.f);
                C[(size_t)(rbase + i * 16 + r) * N + col] = (__bf16)v;
            }
    }
}

// ---- persistent fused recurrence: all 20 steps in one kernel ----
// grid 256 x 512thr. Block bid: rg = bid&7 (rows [rg*64,+64)), cb = bid>>3
// (channels [cb*32,+32) -> 128 gate-cols). 8 waves: cq = w&3 (32-col quarter),
// kh = w>>2 (K half). Whh held in REGISTERS (128 VGPR: 16 ksubs x 2 colfrags).
// A (h rows) staged per 64-k chunk in XOR-swizzled LDS. c-state in registers.
// Per-row-group barrier via monotonic global counter (32 blocks each).
__global__ __launch_bounds__(512) void lstm_all(
    const __bf16* __restrict__ Whh, const __bf16* __restrict__ Xg,
    __bf16* __restrict__ hA, __bf16* __restrict__ hB,
    __bf16* __restrict__ sel,
    const int* __restrict__ dl_s, const int* __restrict__ perm,
    const int* __restrict__ n_act, int* __restrict__ gctr)
{
    __shared__ __bf16 As[64 * 128];    // 16 KB, swizzled granules
    __shared__ float  Cs[64 * 128];    // 32 KB, K-half combine + gate read
    const int tid = threadIdx.x;
    const int w = tid >> 6, lane = tid & 63;
    const int bid = blockIdx.x;
    const int rg = bid & 7;
    const int cb = bid >> 3;
    const int ch0 = cb * 32;
    const int cq = w & 3, kh = w >> 2;
    const int m0r = rg * 64;

    // ---- Whh slice -> registers (one time) ----
    bf16x8 breg[16][2];
#pragma unroll
    for (int s = 0; s < 16; ++s)
#pragma unroll
        for (int n = 0; n < 2; ++n) {
            const int c = cq * 32 + n * 16 + (lane & 15);        // block col 0..127
            const int R = (c >> 5) * 1024 + ch0 + (c & 31);      // Whh row
            const int k = kh * 512 + s * 32 + (lane >> 4) * 8;
            breg[s][n] = *(const bf16x8*)(Whh + (size_t)R * 1024 + k);
        }

    // epilogue statics: thread -> (row eb, 4 channels at ech)
    const int eb  = tid >> 3;
    const int ech = (tid & 7) * 4;
    const int sb  = m0r + eb;
    const int mydl  = dl_s[sb];
    const int operm = perm[sb];
    float creg[4] = {0.f, 0.f, 0.f, 0.f};

    // staging statics: thread -> (row sr, 16B piece seg of each K-half)
    const int sr  = tid >> 3;
    const int seg = tid & 7;

    for (int t = 0; t < 20; ++t) {
        const __bf16* hin  = (t & 1) ? hB : hA;
        __bf16*       hout = (t & 1) ? hA : hB;
        const int nt = n_act[t];
        if (m0r < nt) {
            f32x4 acc[4][2] = {};
            const __bf16* hrow = hin + (size_t)(m0r + sr) * 1024;
            bf16x8 p0 = *(const bf16x8*)(hrow + seg * 8);
            bf16x8 p1 = *(const bf16x8*)(hrow + 512 + seg * 8);
#pragma unroll
            for (int i = 0; i < 8; ++i) {
                __syncthreads();
                *(bf16x8*)((char*)As + sr * 256 + ((seg ^ (sr & 7)) << 4)) = p0;
                *(bf16x8*)((char*)As + sr * 256 + (((seg + 8) ^ (sr & 7)) << 4)) = p1;
                __syncthreads();
                if (i < 7) {
                    p0 = *(const bf16x8*)(hrow + (i + 1) * 64 + seg * 8);
                    p1 = *(const bf16x8*)(hrow + 512 + (i + 1) * 64 + seg * 8);
                }
#pragma unroll
                for (int s = 0; s < 2; ++s) {
                    bf16x8 af[4];
#pragma unroll
                    for (int f = 0; f < 4; ++f) {
                        const int row = f * 16 + (lane & 15);
                        const int g   = kh * 8 + s * 4 + (lane >> 4);   // granule
                        af[f] = *(const bf16x8*)((char*)As + row * 256 +
                                                 ((g ^ (row & 7)) << 4));
                    }
#pragma unroll
                    for (int f = 0; f < 4; ++f)
#pragma unroll
                        for (int n = 0; n < 2; ++n)
                            acc[f][n] = MFMA16(af[f], breg[i * 2 + s][n], acc[f][n], 0, 0, 0);
                }
            }
            // combine K halves in Cs
            __syncthreads();
            const int crb = (lane >> 4) * 4;
            const int ccl = cq * 32 + (lane & 15);
            if (kh == 0) {
#pragma unroll
                for (int f = 0; f < 4; ++f)
#pragma unroll
                    for (int n = 0; n < 2; ++n)
#pragma unroll
                        for (int r = 0; r < 4; ++r)
                            Cs[(f * 16 + crb + r) * 128 + ccl + n * 16] = acc[f][n][r];
            }
            __syncthreads();
            if (kh == 1) {
#pragma unroll
                for (int f = 0; f < 4; ++f)
#pragma unroll
                    for (int n = 0; n < 2; ++n)
#pragma unroll
                        for (int r = 0; r < 4; ++r)
                            Cs[(f * 16 + crb + r) * 128 + ccl + n * 16] += acc[f][n][r];
            }
            __syncthreads();
            // gates: thread owns (eb, ech..ech+3); Xg cols are ch*4+g (32B chunk)
            {
                const __bf16* xg = Xg + (size_t)(t * 512 + sb) * 4096 + (size_t)(ch0 + ech) * 4;
                bf16x8 x0 = *(const bf16x8*)xg;
                bf16x8 x1 = *(const bf16x8*)(xg + 8);
                bf16x4 hv4;
#pragma unroll
                for (int j = 0; j < 4; ++j) {
                    float gi, gf, gg, go;
                    if (j == 0) { gi = (float)x0[0]; gf = (float)x0[1]; gg = (float)x0[2]; go = (float)x0[3]; }
                    if (j == 1) { gi = (float)x0[4]; gf = (float)x0[5]; gg = (float)x0[6]; go = (float)x0[7]; }
                    if (j == 2) { gi = (float)x1[0]; gf = (float)x1[1]; gg = (float)x1[2]; go = (float)x1[3]; }
                    if (j == 3) { gi = (float)x1[4]; gf = (float)x1[5]; gg = (float)x1[6]; go = (float)x1[7]; }
                    gi += Cs[eb * 128 + 0 * 32 + ech + j];
                    gf += Cs[eb * 128 + 1 * 32 + ech + j];
                    gg += Cs[eb * 128 + 2 * 32 + ech + j];
                    go += Cs[eb * 128 + 3 * 32 + ech + j];
                    const float cn = fsig(gf) * creg[j] + fsig(gi) * ftanh(gg);
                    creg[j] = cn;
                    hv4[j] = (__bf16)(fsig(go) * ftanh(cn));
                }
                *(bf16x4*)(hout + (size_t)sb * 1024 + ch0 + ech) = hv4;
                if (t == mydl - 1)
                    *(bf16x4*)(sel + (size_t)operm * 1024 + ch0 + ech) = hv4;
            }
        }
        // ---- row-group barrier (ALL blocks, every t) ----
        __threadfence();
        __syncthreads();
        if (tid == 0) {
            atomicAdd(gctr + rg * 16, 1);
            while (atomicAdd(gctr + rg * 16, 0) < 32 * (t + 1))
                __builtin_amdgcn_s_sleep(8);
        }
        __syncthreads();
        __threadfence();
    }
}

// ---- final tiny layer ----
__global__ __launch_bounds__(256) void mlp2(
    const __bf16* __restrict__ y1, const float* __restrict__ W2,
    const float* __restrict__ b2, float* __restrict__ out)
{
    int b = blockIdx.x, tid = threadIdx.x;
    float s0 = 0.f, s1 = 0.f;
    for (int k = tid; k < 1024; k += 256) {
        float v = (float)y1[(size_t)b * 1024 + k];
        s0 += v * W2[k];
        s1 += v * W2[1024 + k];
    }
#pragma unroll
    for (int o = 32; o > 0; o >>= 1) {
        s0 += __shfl_down(s0, o);
        s1 += __shfl_down(s1, o);
    }
    __shared__ float red[8];
    if ((tid & 63) == 0) { red[(tid >> 6) * 2] = s0; red[(tid >> 6) * 2 + 1] = s1; }
    __syncthreads();
    if (tid == 0) {
        float a0 = red[0] + red[2] + red[4] + red[6] + b2[0];
        float a1 = red[1] + red[3] + red[5] + red[7] + b2[1];
        out[b * 2 + 0] = fmaxf(a0, 0.f);
        out[b * 2 + 1] = fmaxf(a1, 0.f);
    }
}

extern "C" void kernel_launch(void* const* d_in, const int* in_sizes, int n_in,
                              void* d_out, int out_size, void* d_ws, size_t ws_size,
                              hipStream_t stream) {
    const int*   ent     = (const int*)d_in[0];
    const int*   rel     = (const int*)d_in[1];
    const int*   dlen    = (const int*)d_in[3];
    const float* ent_emb = (const float*)d_in[4];
    const float* rel_emb = (const float*)d_in[5];
    const float* Wih     = (const float*)d_in[6];
    const float* Whh     = (const float*)d_in[7];
    const float* bih     = (const float*)d_in[8];
    const float* bhh     = (const float*)d_in[9];
    const float* W1      = (const float*)d_in[10];
    const float* b1      = (const float*)d_in[11];
    const float* W2      = (const float*)d_in[12];
    const float* b2      = (const float*)d_in[13];
    float* out = (float*)d_out;

    char* ws = (char*)d_ws;
    size_t off = 0;
    auto alloc = [&](size_t bytes) -> void* {
        void* p = ws + off; off += (bytes + 255) & ~(size_t)255; return p;
    };
    __bf16* xbf    = (__bf16*)alloc(10240UL * 1024 * 2);  // [t*512+sb][1024]
    __bf16* Wih1   = (__bf16*)alloc(4096UL * 1024 * 2);
    __bf16* Whh1   = (__bf16*)alloc(4096UL * 1024 * 2);
    __bf16* W1b    = (__bf16*)alloc(1024UL * 1024 * 2);
    float*  bsum_p = (float*) alloc(4096UL * 4);
    __bf16* Xg     = (__bf16*)alloc(10240UL * 4096 * 2);  // [t*512+sb][ch*4+g]
    __bf16* hA     = (__bf16*)alloc(512UL * 1024 * 2);
    __bf16* hB     = (__bf16*)alloc(512UL * 1024 * 2);
    __bf16* selb   = (__bf16*)alloc(512UL * 1024 * 2);
    __bf16* y1b    = (__bf16*)alloc(512UL * 1024 * 2);
    int*    permb  = (int*)   alloc(512 * 4);
    int*    dl_s   = (int*)   alloc(512 * 4);
    int*    n_act  = (int*)   alloc(32 * 4);
    int*    gctr   = (int*)   alloc(128 * 4);

    sort_rows<<<dim3(1), dim3(512), 0, stream>>>(dlen, permb, dl_s, n_act);
    convert_weights<<<dim3(4096), dim3(256), 0, stream>>>(
        Wih, Whh, W1, bih, bhh, Wih1, Whh1, W1b, bsum_p);
    gather_x<<<dim3(10240), dim3(256), 0, stream>>>(
        ent, rel, ent_emb, rel_emb, permb, xbf);
    // Xg = x @ W_ih[1]^T + (b_ih+b_hh), gate-interleaved cols, dead slabs skipped
    gemm_bias<false, true, true><<<dim3(80, 32), dim3(256), 0, stream>>>(
        xbf, Wih1, bsum_p, Xg, 10240, 4096, 1024, n_act);

    hipMemsetAsync(hA, 0, 512UL * 1024 * 2, stream);
    hipMemsetAsync(hB, 0, 512UL * 1024 * 2, stream);
    hipMemsetAsync(gctr, 0, 128 * 4, stream);

    lstm_all<<<dim3(256), dim3(512), 0, stream>>>(
        Whh1, Xg, hA, hB, selb, dl_s, permb, n_act, gctr);

    gemm_bias<true, false, false><<<dim3(4, 8), dim3(256), 0, stream>>>(
        selb, W1b, b1, y1b, 512, 1024, 1024, nullptr);
    mlp2<<<dim3(512), dim3(256), 0, stream>>>(y1b, W2, b2, out);
}

// Round 4
// 1708.885 us; speedup vs baseline: 1.0077x; 1.0077x over previous
//
#include <hip/hip_runtime.h>

typedef __bf16 bf16x8 __attribute__((ext_vector_type(8)));
typedef __bf16 bf16x4 __attribute__((ext_vector_type(4)));
typedef float  f32x4  __attribute__((ext_vector_type(4)));

#define MFMA16 __builtin_amdgcn_mfma_f32_16x16x32_bf16
#define GLL16(g, l) __builtin_amdgcn_global_load_lds( \
    (const __attribute__((address_space(1))) void*)(g), \
    (__attribute__((address_space(3))) void*)(l), 16, 0, 0)

__device__ __forceinline__ float fsig(float x)  { return 1.f / (1.f + __expf(-x)); }
__device__ __forceinline__ float ftanh(float x) { return 1.f - 2.f / (__expf(2.f * x) + 1.f); }

// B=512, T=20, D=1024, H=1024, 4H=4096. Layer 0 of the LSTM is dead code.

// ---- sort batch rows by dlen descending (stable, deterministic) ----
__global__ __launch_bounds__(512) void sort_rows(
    const int* __restrict__ dlen, int* __restrict__ perm,
    int* __restrict__ dl_s, int* __restrict__ n_act)
{
    __shared__ int sdl[512];
    const int b = threadIdx.x;
    const int dl = dlen[b];
    sdl[b] = dl;
    __syncthreads();
    int pos = 0;
    for (int j = 0; j < 512; ++j) {
        const int dj = sdl[j];
        pos += (dj > dl) || (dj == dl && j < b);
    }
    perm[pos] = b;
    dl_s[pos] = dl;
    if (b < 20) {
        int cnt = 0;
        for (int j = 0; j < 512; ++j) cnt += (sdl[j] > b);
        n_act[b] = cnt;           // #rows active at step t (always n_act[0]==512)
    }
}

// ---- convert layer-1 weights + W1 to bf16; bsum_p = permuted (b_ih+b_hh) ----
// bsum_p[c] is for Xg column layout c = ch*4 + gate.
__global__ __launch_bounds__(256) void convert_weights(
    const float* __restrict__ Wih, const float* __restrict__ Whh,
    const float* __restrict__ W1,  const float* __restrict__ bih,
    const float* __restrict__ bhh,
    __bf16* __restrict__ Wih1, __bf16* __restrict__ Whh1,
    __bf16* __restrict__ W1b,  float* __restrict__ bsum_p)
{
    const size_t L1 = 4096UL * 1024UL;
    size_t i = (size_t)blockIdx.x * 256 + threadIdx.x;   // 0 .. 1048575
    float4 a = *(const float4*)(Wih + L1 + i * 4);
    float4 b = *(const float4*)(Whh + L1 + i * 4);
    bf16x4 av = { (__bf16)a.x, (__bf16)a.y, (__bf16)a.z, (__bf16)a.w };
    bf16x4 bv = { (__bf16)b.x, (__bf16)b.y, (__bf16)b.z, (__bf16)b.w };
    *(bf16x4*)(Wih1 + i * 4) = av;
    *(bf16x4*)(Whh1 + i * 4) = bv;
    W1b[i] = (__bf16)W1[i];
    if (i < 4096) {
        const int m = ((int)i & 3) * 1024 + ((int)i >> 2);  // gate*1024 + ch
        bsum_p[i] = bih[4096 + m] + bhh[4096 + m];
    }
}

// ---- gather x in SORTED row order: xbf[t*512+sb] = [rel_emb | ent_emb] ----
__global__ __launch_bounds__(256) void gather_x(
    const int* __restrict__ ent, const int* __restrict__ rel,
    const float* __restrict__ ent_emb, const float* __restrict__ rel_emb,
    const int* __restrict__ perm, __bf16* __restrict__ xbf)
{
    int bid = blockIdx.x;              // sb*20 + t
    int sb = bid / 20, t = bid - sb * 20;
    int bo = perm[sb];
    int tid = threadIdx.x;
    int col = (tid & 127) * 4;
    const float* src = (tid < 128)
        ? (rel_emb + (size_t)rel[bo * 20 + t] * 512 + col)
        : (ent_emb + (size_t)ent[bo * 20 + t] * 512 + col);
    float4 v = *(const float4*)src;
    bf16x4 o = { (__bf16)v.x, (__bf16)v.y, (__bf16)v.z, (__bf16)v.w };
    int outcol = (tid < 128) ? col : (512 + col);
    *(bf16x4*)(xbf + (size_t)(t * 512 + sb) * 1024 + outcol) = o;
}

// ---- bf16 MFMA GEMM: C[M,N] = A[M,K] @ B[N,K]^T + bias, opt ReLU ----
// PERM: B-row for output col c is (c&3)*1024 + (c>>2)  (gate-interleaved Xg cols)
// SKIP: early-exit blocks whose 128-row slab is entirely dead (rows sorted per t)
template<bool RELU, bool PERM, bool SKIP>
__global__ __launch_bounds__(256) void gemm_bias(
    const __bf16* __restrict__ A, const __bf16* __restrict__ B,
    const float* __restrict__ bias, __bf16* __restrict__ C,
    int M, int N, int K, const int* __restrict__ nact)
{
    const int m0 = blockIdx.x * 128, n0 = blockIdx.y * 128;
    if (SKIP) {
        if ((m0 & 511) >= nact[m0 >> 9]) return;
    }
    __shared__ __bf16 As[128 * 64];
    __shared__ __bf16 Bs[128 * 64];
    const int tid = threadIdx.x;
    const int w = tid >> 6, lane = tid & 63;
    const int wr = (w >> 1) * 64, wc = (w & 1) * 64;
    const int srow = lane >> 3;
    const int scol = (lane & 7) * 8;

    f32x4 acc[4][4] = {};

    for (int k0 = 0; k0 < K; k0 += 64) {
#pragma unroll
        for (int j = 0; j < 4; ++j) {
            const int r = (w * 4 + j) * 8 + srow;        // 0..127
            GLL16(A + (size_t)(m0 + r) * K + k0 + scol, As + (w * 4 + j) * 512);
            const int rr = n0 + r;
            const int R = PERM ? ((rr & 3) * 1024 + (rr >> 2)) : rr;
            GLL16(B + (size_t)R * K + k0 + scol, Bs + (w * 4 + j) * 512);
        }
        __syncthreads();
#pragma unroll
        for (int ks = 0; ks < 2; ++ks) {
            const int ko = ks * 32 + (lane >> 4) * 8;
            bf16x8 af[4], bb[4];
#pragma unroll
            for (int i = 0; i < 4; ++i)
                af[i] = *(const bf16x8*)&As[(wr + i * 16 + (lane & 15)) * 64 + ko];
#pragma unroll
            for (int j = 0; j < 4; ++j)
                bb[j] = *(const bf16x8*)&Bs[(wc + j * 16 + (lane & 15)) * 64 + ko];
#pragma unroll
            for (int i = 0; i < 4; ++i)
#pragma unroll
                for (int j = 0; j < 4; ++j)
                    acc[i][j] = MFMA16(af[i], bb[j], acc[i][j], 0, 0, 0);
        }
        __syncthreads();
    }
    const int rbase = m0 + wr + (lane >> 4) * 4;
    const int cbase = n0 + wc + (lane & 15);
#pragma unroll
    for (int j = 0; j < 4; ++j) {
        const int col = cbase + j * 16;
        const float bv = bias[col];
#pragma unroll
        for (int i = 0; i < 4; ++i)
#pragma unroll
            for (int r = 0; r < 4; ++r) {
                float v = acc[i][j][r] + bv;
                if (RELU) v = fmaxf(v, 0.f);
                C[(size_t)(rbase + i * 16 + r) * N + col] = (__bf16)v;
            }
    }
}

// ---- persistent fused recurrence: all 20 steps in one kernel ----
// grid 256 x 512thr. Block bid: rg = bid&7 (rows [rg*64,+64)), cb = bid>>3
// (channels [cb*32,+32) -> 128 gate-cols). 8 waves: cq = w&3 (32-col quarter),
// kh = w>>2 (K half). Whh held in REGISTERS (128 VGPR: 16 ksubs x 2 colfrags).
// __launch_bounds__(512, 2): 2 waves/EU = 1 block/CU -> VGPR cap 256, so the
// 128-VGPR breg tile is NOT spilled (R3 failure: default bounds capped at ~104
// VGPR and spilled breg to scratch -> MfmaUtil 1.3%).
__global__ __launch_bounds__(512, 2) void lstm_all(
    const __bf16* __restrict__ Whh, const __bf16* __restrict__ Xg,
    __bf16* __restrict__ hA, __bf16* __restrict__ hB,
    __bf16* __restrict__ sel,
    const int* __restrict__ dl_s, const int* __restrict__ perm,
    const int* __restrict__ n_act, int* __restrict__ gctr)
{
    __shared__ __bf16 As[64 * 128];    // 16 KB, swizzled granules
    __shared__ float  Cs[64 * 128];    // 32 KB, K-half combine + gate read
    const int tid = threadIdx.x;
    const int w = tid >> 6, lane = tid & 63;
    const int bid = blockIdx.x;
    const int rg = bid & 7;
    const int cb = bid >> 3;
    const int ch0 = cb * 32;
    const int cq = w & 3, kh = w >> 2;
    const int m0r = rg * 64;

    // ---- Whh slice -> registers (one time) ----
    bf16x8 breg[16][2];
#pragma unroll
    for (int s = 0; s < 16; ++s)
#pragma unroll
        for (int n = 0; n < 2; ++n) {
            const int c = cq * 32 + n * 16 + (lane & 15);        // block col 0..127
            const int R = (c >> 5) * 1024 + ch0 + (c & 31);      // Whh row
            const int k = kh * 512 + s * 32 + (lane >> 4) * 8;
            breg[s][n] = *(const bf16x8*)(Whh + (size_t)R * 1024 + k);
        }

    // epilogue statics: thread -> (row eb, 4 channels at ech)
    const int eb  = tid >> 3;
    const int ech = (tid & 7) * 4;
    const int sb  = m0r + eb;
    const int mydl  = dl_s[sb];
    const int operm = perm[sb];
    float creg[4] = {0.f, 0.f, 0.f, 0.f};

    // staging statics: thread -> (row sr, 16B piece seg of each K-half)
    const int sr  = tid >> 3;
    const int seg = tid & 7;

    for (int t = 0; t < 20; ++t) {
        const __bf16* hin  = (t & 1) ? hB : hA;
        __bf16*       hout = (t & 1) ? hA : hB;
        const int nt = n_act[t];
        if (m0r < nt) {
            f32x4 acc[4][2] = {};
            const __bf16* hrow = hin + (size_t)(m0r + sr) * 1024;
            bf16x8 p0 = *(const bf16x8*)(hrow + seg * 8);
            bf16x8 p1 = *(const bf16x8*)(hrow + 512 + seg * 8);
#pragma unroll
            for (int i = 0; i < 8; ++i) {
                __syncthreads();
                *(bf16x8*)((char*)As + sr * 256 + ((seg ^ (sr & 7)) << 4)) = p0;
                *(bf16x8*)((char*)As + sr * 256 + (((seg + 8) ^ (sr & 7)) << 4)) = p1;
                __syncthreads();
                if (i < 7) {
                    p0 = *(const bf16x8*)(hrow + (i + 1) * 64 + seg * 8);
                    p1 = *(const bf16x8*)(hrow + 512 + (i + 1) * 64 + seg * 8);
                }
#pragma unroll
                for (int s = 0; s < 2; ++s) {
                    bf16x8 af[4];
#pragma unroll
                    for (int f = 0; f < 4; ++f) {
                        const int row = f * 16 + (lane & 15);
                        const int g   = kh * 8 + s * 4 + (lane >> 4);   // granule
                        af[f] = *(const bf16x8*)((char*)As + row * 256 +
                                                 ((g ^ (row & 7)) << 4));
                    }
#pragma unroll
                    for (int f = 0; f < 4; ++f)
#pragma unroll
                        for (int n = 0; n < 2; ++n)
                            acc[f][n] = MFMA16(af[f], breg[i * 2 + s][n], acc[f][n], 0, 0, 0);
                }
            }
            // combine K halves in Cs
            __syncthreads();
            const int crb = (lane >> 4) * 4;
            const int ccl = cq * 32 + (lane & 15);
            if (kh == 0) {
#pragma unroll
                for (int f = 0; f < 4; ++f)
#pragma unroll
                    for (int n = 0; n < 2; ++n)
#pragma unroll
                        for (int r = 0; r < 4; ++r)
                            Cs[(f * 16 + crb + r) * 128 + ccl + n * 16] = acc[f][n][r];
            }
            __syncthreads();
            if (kh == 1) {
#pragma unroll
                for (int f = 0; f < 4; ++f)
#pragma unroll
                    for (int n = 0; n < 2; ++n)
#pragma unroll
                        for (int r = 0; r < 4; ++r)
                            Cs[(f * 16 + crb + r) * 128 + ccl + n * 16] += acc[f][n][r];
            }
            __syncthreads();
            // gates: thread owns (eb, ech..ech+3); Xg cols are ch*4+g (32B chunk)
            {
                const __bf16* xg = Xg + (size_t)(t * 512 + sb) * 4096 + (size_t)(ch0 + ech) * 4;
                bf16x8 x0 = *(const bf16x8*)xg;
                bf16x8 x1 = *(const bf16x8*)(xg + 8);
                bf16x4 hv4;
#pragma unroll
                for (int j = 0; j < 4; ++j) {
                    float gi, gf, gg, go;
                    if (j == 0) { gi = (float)x0[0]; gf = (float)x0[1]; gg = (float)x0[2]; go = (float)x0[3]; }
                    if (j == 1) { gi = (float)x0[4]; gf = (float)x0[5]; gg = (float)x0[6]; go = (float)x0[7]; }
                    if (j == 2) { gi = (float)x1[0]; gf = (float)x1[1]; gg = (float)x1[2]; go = (float)x1[3]; }
                    if (j == 3) { gi = (float)x1[4]; gf = (float)x1[5]; gg = (float)x1[6]; go = (float)x1[7]; }
                    gi += Cs[eb * 128 + 0 * 32 + ech + j];
                    gf += Cs[eb * 128 + 1 * 32 + ech + j];
                    gg += Cs[eb * 128 + 2 * 32 + ech + j];
                    go += Cs[eb * 128 + 3 * 32 + ech + j];
                    const float cn = fsig(gf) * creg[j] + fsig(gi) * ftanh(gg);
                    creg[j] = cn;
                    hv4[j] = (__bf16)(fsig(go) * ftanh(cn));
                }
                *(bf16x4*)(hout + (size_t)sb * 1024 + ch0 + ech) = hv4;
                if (t == mydl - 1)
                    *(bf16x4*)(sel + (size_t)operm * 1024 + ch0 + ech) = hv4;
            }
        }
        // ---- row-group barrier (ALL blocks, every t) ----
        __threadfence();
        __syncthreads();
        if (tid == 0) {
            atomicAdd(gctr + rg * 16, 1);
            while (atomicAdd(gctr + rg * 16, 0) < 32 * (t + 1))
                __builtin_amdgcn_s_sleep(8);
        }
        __syncthreads();
        __threadfence();
    }
}

// ---- final tiny layer ----
__global__ __launch_bounds__(256) void mlp2(
    const __bf16* __restrict__ y1, const float* __restrict__ W2,
    const float* __restrict__ b2, float* __restrict__ out)
{
    int b = blockIdx.x, tid = threadIdx.x;
    float s0 = 0.f, s1 = 0.f;
    for (int k = tid; k < 1024; k += 256) {
        float v = (float)y1[(size_t)b * 1024 + k];
        s0 += v * W2[k];
        s1 += v * W2[1024 + k];
    }
#pragma unroll
    for (int o = 32; o > 0; o >>= 1) {
        s0 += __shfl_down(s0, o);
        s1 += __shfl_down(s1, o);
    }
    __shared__ float red[8];
    if ((tid & 63) == 0) { red[(tid >> 6) * 2] = s0; red[(tid >> 6) * 2 + 1] = s1; }
    __syncthreads();
    if (tid == 0) {
        float a0 = red[0] + red[2] + red[4] + red[6] + b2[0];
        float a1 = red[1] + red[3] + red[5] + red[7] + b2[1];
        out[b * 2 + 0] = fmaxf(a0, 0.f);
        out[b * 2 + 1] = fmaxf(a1, 0.f);
    }
}

extern "C" void kernel_launch(void* const* d_in, const int* in_sizes, int n_in,
                              void* d_out, int out_size, void* d_ws, size_t ws_size,
                              hipStream_t stream) {
    const int*   ent     = (const int*)d_in[0];
    const int*   rel     = (const int*)d_in[1];
    const int*   dlen    = (const int*)d_in[3];
    const float* ent_emb = (const float*)d_in[4];
    const float* rel_emb = (const float*)d_in[5];
    const float* Wih     = (const float*)d_in[6];
    const float* Whh     = (const float*)d_in[7];
    const float* bih     = (const float*)d_in[8];
    const float* bhh     = (const float*)d_in[9];
    const float* W1      = (const float*)d_in[10];
    const float* b1      = (const float*)d_in[11];
    const float* W2      = (const float*)d_in[12];
    const float* b2      = (const float*)d_in[13];
    float* out = (float*)d_out;

    char* ws = (char*)d_ws;
    size_t off = 0;
    auto alloc = [&](size_t bytes) -> void* {
        void* p = ws + off; off += (bytes + 255) & ~(size_t)255; return p;
    };
    __bf16* xbf    = (__bf16*)alloc(10240UL * 1024 * 2);  // [t*512+sb][1024]
    __bf16* Wih1   = (__bf16*)alloc(4096UL * 1024 * 2);
    __bf16* Whh1   = (__bf16*)alloc(4096UL * 1024 * 2);
    __bf16* W1b    = (__bf16*)alloc(1024UL * 1024 * 2);
    float*  bsum_p = (float*) alloc(4096UL * 4);
    __bf16* Xg     = (__bf16*)alloc(10240UL * 4096 * 2);  // [t*512+sb][ch*4+g]
    __bf16* hA     = (__bf16*)alloc(512UL * 1024 * 2);
    __bf16* hB     = (__bf16*)alloc(512UL * 1024 * 2);
    __bf16* selb   = (__bf16*)alloc(512UL * 1024 * 2);
    __bf16* y1b    = (__bf16*)alloc(512UL * 1024 * 2);
    int*    permb  = (int*)   alloc(512 * 4);
    int*    dl_s   = (int*)   alloc(512 * 4);
    int*    n_act  = (int*)   alloc(32 * 4);
    int*    gctr   = (int*)   alloc(128 * 4);

    sort_rows<<<dim3(1), dim3(512), 0, stream>>>(dlen, permb, dl_s, n_act);
    convert_weights<<<dim3(4096), dim3(256), 0, stream>>>(
        Wih, Whh, W1, bih, bhh, Wih1, Whh1, W1b, bsum_p);
    gather_x<<<dim3(10240), dim3(256), 0, stream>>>(
        ent, rel, ent_emb, rel_emb, permb, xbf);
    // Xg = x @ W_ih[1]^T + (b_ih+b_hh), gate-interleaved cols, dead slabs skipped
    gemm_bias<false, true, true><<<dim3(80, 32), dim3(256), 0, stream>>>(
        xbf, Wih1, bsum_p, Xg, 10240, 4096, 1024, n_act);

    hipMemsetAsync(hA, 0, 512UL * 1024 * 2, stream);
    hipMemsetAsync(hB, 0, 512UL * 1024 * 2, stream);
    hipMemsetAsync(gctr, 0, 128 * 4, stream);

    lstm_all<<<dim3(256), dim3(512), 0, stream>>>(
        Whh1, Xg, hA, hB, selb, dl_s, permb, n_act, gctr);

    gemm_bias<true, false, false><<<dim3(4, 8), dim3(256), 0, stream>>>(
        selb, W1b, b1, y1b, 512, 1024, 1024, nullptr);
    mlp2<<<dim3(512), dim3(256), 0, stream>>>(y1b, W2, b2, out);
}

// Round 5
// 1697.613 us; speedup vs baseline: 1.0144x; 1.0066x over previous
//
#include <hip/hip_runtime.h>

typedef __bf16 bf16x8 __attribute__((ext_vector_type(8)));
typedef __bf16 bf16x4 __attribute__((ext_vector_type(4)));
typedef float  f32x4  __attribute__((ext_vector_type(4)));

#define MFMA16 __builtin_amdgcn_mfma_f32_16x16x32_bf16
#define GLL16(g, l) __builtin_amdgcn_global_load_lds( \
    (const __attribute__((address_space(1))) void*)(g), \
    (__attribute__((address_space(3))) void*)(l), 16, 0, 0)

__device__ __forceinline__ float fsig(float x)  { return 1.f / (1.f + __expf(-x)); }
__device__ __forceinline__ float ftanh(float x) { return 1.f - 2.f / (__expf(2.f * x) + 1.f); }

// B=512, T=20, D=1024, H=1024, 4H=4096. Layer 0 of the LSTM is dead code.

// ---- sort batch rows by dlen descending (stable, deterministic) ----
__global__ __launch_bounds__(512) void sort_rows(
    const int* __restrict__ dlen, int* __restrict__ perm,
    int* __restrict__ dl_s, int* __restrict__ n_act)
{
    __shared__ int sdl[512];
    const int b = threadIdx.x;
    const int dl = dlen[b];
    sdl[b] = dl;
    __syncthreads();
    int pos = 0;
    for (int j = 0; j < 512; ++j) {
        const int dj = sdl[j];
        pos += (dj > dl) || (dj == dl && j < b);
    }
    perm[pos] = b;
    dl_s[pos] = dl;
    if (b < 20) {
        int cnt = 0;
        for (int j = 0; j < 512; ++j) cnt += (sdl[j] > b);
        n_act[b] = cnt;           // #rows active at step t (always n_act[0]==512)
    }
}

// ---- convert layer-1 weights + W1 to bf16; bsum_p = permuted (b_ih+b_hh) ----
// bsum_p[c] is for Xg column layout c = ch*4 + gate.
__global__ __launch_bounds__(256) void convert_weights(
    const float* __restrict__ Wih, const float* __restrict__ Whh,
    const float* __restrict__ W1,  const float* __restrict__ bih,
    const float* __restrict__ bhh,
    __bf16* __restrict__ Wih1, __bf16* __restrict__ Whh1,
    __bf16* __restrict__ W1b,  float* __restrict__ bsum_p)
{
    const size_t L1 = 4096UL * 1024UL;
    size_t i = (size_t)blockIdx.x * 256 + threadIdx.x;   // 0 .. 1048575
    float4 a = *(const float4*)(Wih + L1 + i * 4);
    float4 b = *(const float4*)(Whh + L1 + i * 4);
    bf16x4 av = { (__bf16)a.x, (__bf16)a.y, (__bf16)a.z, (__bf16)a.w };
    bf16x4 bv = { (__bf16)b.x, (__bf16)b.y, (__bf16)b.z, (__bf16)b.w };
    *(bf16x4*)(Wih1 + i * 4) = av;
    *(bf16x4*)(Whh1 + i * 4) = bv;
    W1b[i] = (__bf16)W1[i];
    if (i < 4096) {
        const int m = ((int)i & 3) * 1024 + ((int)i >> 2);  // gate*1024 + ch
        bsum_p[i] = bih[4096 + m] + bhh[4096 + m];
    }
}

// ---- gather x in SORTED row order: xbf[t*512+sb] = [rel_emb | ent_emb] ----
__global__ __launch_bounds__(256) void gather_x(
    const int* __restrict__ ent, const int* __restrict__ rel,
    const float* __restrict__ ent_emb, const float* __restrict__ rel_emb,
    const int* __restrict__ perm, __bf16* __restrict__ xbf)
{
    int bid = blockIdx.x;              // sb*20 + t
    int sb = bid / 20, t = bid - sb * 20;
    int bo = perm[sb];
    int tid = threadIdx.x;
    int col = (tid & 127) * 4;
    const float* src = (tid < 128)
        ? (rel_emb + (size_t)rel[bo * 20 + t] * 512 + col)
        : (ent_emb + (size_t)ent[bo * 20 + t] * 512 + col);
    float4 v = *(const float4*)src;
    bf16x4 o = { (__bf16)v.x, (__bf16)v.y, (__bf16)v.z, (__bf16)v.w };
    int outcol = (tid < 128) ? col : (512 + col);
    *(bf16x4*)(xbf + (size_t)(t * 512 + sb) * 1024 + outcol) = o;
}

// ---- bf16 MFMA GEMM: C[M,N] = A[M,K] @ B[N,K]^T + bias, opt ReLU ----
// PERM: B-row for output col c is (c&3)*1024 + (c>>2)  (gate-interleaved Xg cols)
// SKIP: early-exit blocks whose 128-row slab is entirely dead (rows sorted per t)
template<bool RELU, bool PERM, bool SKIP>
__global__ __launch_bounds__(256) void gemm_bias(
    const __bf16* __restrict__ A, const __bf16* __restrict__ B,
    const float* __restrict__ bias, __bf16* __restrict__ C,
    int M, int N, int K, const int* __restrict__ nact)
{
    const int m0 = blockIdx.x * 128, n0 = blockIdx.y * 128;
    if (SKIP) {
        if ((m0 & 511) >= nact[m0 >> 9]) return;
    }
    __shared__ __bf16 As[128 * 64];
    __shared__ __bf16 Bs[128 * 64];
    const int tid = threadIdx.x;
    const int w = tid >> 6, lane = tid & 63;
    const int wr = (w >> 1) * 64, wc = (w & 1) * 64;
    const int srow = lane >> 3;
    const int scol = (lane & 7) * 8;

    f32x4 acc[4][4] = {};

    for (int k0 = 0; k0 < K; k0 += 64) {
#pragma unroll
        for (int j = 0; j < 4; ++j) {
            const int r = (w * 4 + j) * 8 + srow;        // 0..127
            GLL16(A + (size_t)(m0 + r) * K + k0 + scol, As + (w * 4 + j) * 512);
            const int rr = n0 + r;
            const int R = PERM ? ((rr & 3) * 1024 + (rr >> 2)) : rr;
            GLL16(B + (size_t)R * K + k0 + scol, Bs + (w * 4 + j) * 512);
        }
        __syncthreads();
#pragma unroll
        for (int ks = 0; ks < 2; ++ks) {
            const int ko = ks * 32 + (lane >> 4) * 8;
            bf16x8 af[4], bb[4];
#pragma unroll
            for (int i = 0; i < 4; ++i)
                af[i] = *(const bf16x8*)&As[(wr + i * 16 + (lane & 15)) * 64 + ko];
#pragma unroll
            for (int j = 0; j < 4; ++j)
                bb[j] = *(const bf16x8*)&Bs[(wc + j * 16 + (lane & 15)) * 64 + ko];
#pragma unroll
            for (int i = 0; i < 4; ++i)
#pragma unroll
                for (int j = 0; j < 4; ++j)
                    acc[i][j] = MFMA16(af[i], bb[j], acc[i][j], 0, 0, 0);
        }
        __syncthreads();
    }
    const int rbase = m0 + wr + (lane >> 4) * 4;
    const int cbase = n0 + wc + (lane & 15);
#pragma unroll
    for (int j = 0; j < 4; ++j) {
        const int col = cbase + j * 16;
        const float bv = bias[col];
#pragma unroll
        for (int i = 0; i < 4; ++i)
#pragma unroll
            for (int r = 0; r < 4; ++r) {
                float v = acc[i][j][r] + bv;
                if (RELU) v = fmaxf(v, 0.f);
                C[(size_t)(rbase + i * 16 + r) * N + col] = (__bf16)v;
            }
    }
}

// ---- persistent fused recurrence: all 20 steps in one kernel ----
// Identical dataflow to R3/R4, but the Whh register tile and accumulators are
// NAMED SSA VALUES (no arrays): R3/R4's breg[16][2] was placed in scratch by
// the compiler (rule #20: SROA runs before unroll -> variable-index alloca ->
// localMem), giving VGPR_Count=104 (<128 needed) and MfmaUtil 1.3%.
__global__ __launch_bounds__(512, 2) void lstm_all(
    const __bf16* __restrict__ Whh, const __bf16* __restrict__ Xg,
    __bf16* __restrict__ hA, __bf16* __restrict__ hB,
    __bf16* __restrict__ sel,
    const int* __restrict__ dl_s, const int* __restrict__ perm,
    const int* __restrict__ n_act, int* __restrict__ gctr)
{
    __shared__ __bf16 As[64 * 128];    // 16 KB, swizzled granules
    __shared__ float  Cs[64 * 128];    // 32 KB, K-half combine + gate read
    const int tid = threadIdx.x;
    const int w = tid >> 6, lane = tid & 63;
    const int bid = blockIdx.x;
    const int rg = bid & 7;
    const int cb = bid >> 3;
    const int ch0 = cb * 32;
    const int cq = w & 3, kh = w >> 2;
    const int m0r = rg * 64;

    // ---- Whh slice -> 32 named bf16x8 registers (one time) ----
    const int c0 = cq * 32 + (lane & 15);            // block col, n=0
    const int c1 = c0 + 16;                          // block col, n=1
    const int R0 = (c0 >> 5) * 1024 + ch0 + (c0 & 31);
    const int R1 = (c1 >> 5) * 1024 + ch0 + (c1 & 31);
    const int kb = kh * 512 + (lane >> 4) * 8;
    const __bf16* w0 = Whh + (size_t)R0 * 1024 + kb;
    const __bf16* w1 = Whh + (size_t)R1 * 1024 + kb;

#define BDECL(k) bf16x8 B##k##_0, B##k##_1
    BDECL(0);  BDECL(1);  BDECL(2);  BDECL(3);
    BDECL(4);  BDECL(5);  BDECL(6);  BDECL(7);
    BDECL(8);  BDECL(9);  BDECL(10); BDECL(11);
    BDECL(12); BDECL(13); BDECL(14); BDECL(15);
#define BLOAD(k) \
    B##k##_0 = *(const bf16x8*)(w0 + (k) * 32); \
    B##k##_1 = *(const bf16x8*)(w1 + (k) * 32)
    BLOAD(0);  BLOAD(1);  BLOAD(2);  BLOAD(3);
    BLOAD(4);  BLOAD(5);  BLOAD(6);  BLOAD(7);
    BLOAD(8);  BLOAD(9);  BLOAD(10); BLOAD(11);
    BLOAD(12); BLOAD(13); BLOAD(14); BLOAD(15);

    // epilogue statics: thread -> (row eb, 4 channels at ech)
    const int eb  = tid >> 3;
    const int ech = (tid & 7) * 4;
    const int sb  = m0r + eb;
    const int mydl  = dl_s[sb];
    const int operm = perm[sb];
    float creg[4] = {0.f, 0.f, 0.f, 0.f};

    // staging statics: thread -> (row sr, 16B piece seg of each K-half)
    const int sr  = tid >> 3;
    const int seg = tid & 7;
    const int srm = sr & 7;
    const int lrow = lane & 15;
    const int crb = (lane >> 4) * 4;
    const int ccl = cq * 32 + (lane & 15);

// one 32-k sub-step: load 4 swizzled A-frags, 8 MFMAs into named accs
#define DO_KSUB(k, s) { \
    const int gg = kh * 8 + (s) * 4 + (lane >> 4); \
    bf16x8 af0 = *(const bf16x8*)((char*)As + (lrow     ) * 256 + ((gg ^ (lrow & 7)) << 4)); \
    bf16x8 af1 = *(const bf16x8*)((char*)As + (lrow + 16) * 256 + ((gg ^ (lrow & 7)) << 4)); \
    bf16x8 af2 = *(const bf16x8*)((char*)As + (lrow + 32) * 256 + ((gg ^ (lrow & 7)) << 4)); \
    bf16x8 af3 = *(const bf16x8*)((char*)As + (lrow + 48) * 256 + ((gg ^ (lrow & 7)) << 4)); \
    a00 = MFMA16(af0, B##k##_0, a00, 0, 0, 0); \
    a01 = MFMA16(af0, B##k##_1, a01, 0, 0, 0); \
    a10 = MFMA16(af1, B##k##_0, a10, 0, 0, 0); \
    a11 = MFMA16(af1, B##k##_1, a11, 0, 0, 0); \
    a20 = MFMA16(af2, B##k##_0, a20, 0, 0, 0); \
    a21 = MFMA16(af2, B##k##_1, a21, 0, 0, 0); \
    a30 = MFMA16(af3, B##k##_0, a30, 0, 0, 0); \
    a31 = MFMA16(af3, B##k##_1, a31, 0, 0, 0); }

// one staging iteration: restage As (both K-half chunks), prefetch next, 2 ksubs
#define DO_I(inext, k0, k1) { \
    __syncthreads(); \
    *(bf16x8*)((char*)As + sr * 256 + ((seg ^ srm) << 4)) = p0; \
    *(bf16x8*)((char*)As + sr * 256 + (((seg + 8) ^ srm) << 4)) = p1; \
    __syncthreads(); \
    if ((inext) < 8) { \
        p0 = *(const bf16x8*)(hrow + (inext) * 64 + seg * 8); \
        p1 = *(const bf16x8*)(hrow + 512 + (inext) * 64 + seg * 8); \
    } \
    DO_KSUB(k0, 0); \
    DO_KSUB(k1, 1); }

#define CS_W(f, n, A) { \
    Cs[((f) * 16 + crb + 0) * 128 + ccl + (n) * 16] = A[0]; \
    Cs[((f) * 16 + crb + 1) * 128 + ccl + (n) * 16] = A[1]; \
    Cs[((f) * 16 + crb + 2) * 128 + ccl + (n) * 16] = A[2]; \
    Cs[((f) * 16 + crb + 3) * 128 + ccl + (n) * 16] = A[3]; }
#define CS_A(f, n, A) { \
    Cs[((f) * 16 + crb + 0) * 128 + ccl + (n) * 16] += A[0]; \
    Cs[((f) * 16 + crb + 1) * 128 + ccl + (n) * 16] += A[1]; \
    Cs[((f) * 16 + crb + 2) * 128 + ccl + (n) * 16] += A[2]; \
    Cs[((f) * 16 + crb + 3) * 128 + ccl + (n) * 16] += A[3]; }

    for (int t = 0; t < 20; ++t) {
        const __bf16* hin  = (t & 1) ? hB : hA;
        __bf16*       hout = (t & 1) ? hA : hB;
        const int nt = n_act[t];
        if (m0r < nt) {
            f32x4 a00 = {0.f,0.f,0.f,0.f}, a01 = {0.f,0.f,0.f,0.f};
            f32x4 a10 = {0.f,0.f,0.f,0.f}, a11 = {0.f,0.f,0.f,0.f};
            f32x4 a20 = {0.f,0.f,0.f,0.f}, a21 = {0.f,0.f,0.f,0.f};
            f32x4 a30 = {0.f,0.f,0.f,0.f}, a31 = {0.f,0.f,0.f,0.f};
            const __bf16* hrow = hin + (size_t)(m0r + sr) * 1024;
            bf16x8 p0 = *(const bf16x8*)(hrow + seg * 8);
            bf16x8 p1 = *(const bf16x8*)(hrow + 512 + seg * 8);
            DO_I(1, 0, 1);
            DO_I(2, 2, 3);
            DO_I(3, 4, 5);
            DO_I(4, 6, 7);
            DO_I(5, 8, 9);
            DO_I(6, 10, 11);
            DO_I(7, 12, 13);
            DO_I(8, 14, 15);
            // combine K halves in Cs
            __syncthreads();
            if (kh == 0) {
                CS_W(0, 0, a00); CS_W(0, 1, a01);
                CS_W(1, 0, a10); CS_W(1, 1, a11);
                CS_W(2, 0, a20); CS_W(2, 1, a21);
                CS_W(3, 0, a30); CS_W(3, 1, a31);
            }
            __syncthreads();
            if (kh == 1) {
                CS_A(0, 0, a00); CS_A(0, 1, a01);
                CS_A(1, 0, a10); CS_A(1, 1, a11);
                CS_A(2, 0, a20); CS_A(2, 1, a21);
                CS_A(3, 0, a30); CS_A(3, 1, a31);
            }
            __syncthreads();
            // gates: thread owns (eb, ech..ech+3); Xg cols are ch*4+g (32B chunk)
            {
                const __bf16* xg = Xg + (size_t)(t * 512 + sb) * 4096 + (size_t)(ch0 + ech) * 4;
                bf16x8 x0 = *(const bf16x8*)xg;
                bf16x8 x1 = *(const bf16x8*)(xg + 8);
                bf16x4 hv4;
#pragma unroll
                for (int j = 0; j < 4; ++j) {
                    float gi, gf, gg, go;
                    if (j == 0) { gi = (float)x0[0]; gf = (float)x0[1]; gg = (float)x0[2]; go = (float)x0[3]; }
                    if (j == 1) { gi = (float)x0[4]; gf = (float)x0[5]; gg = (float)x0[6]; go = (float)x0[7]; }
                    if (j == 2) { gi = (float)x1[0]; gf = (float)x1[1]; gg = (float)x1[2]; go = (float)x1[3]; }
                    if (j == 3) { gi = (float)x1[4]; gf = (float)x1[5]; gg = (float)x1[6]; go = (float)x1[7]; }
                    gi += Cs[eb * 128 + 0 * 32 + ech + j];
                    gf += Cs[eb * 128 + 1 * 32 + ech + j];
                    gg += Cs[eb * 128 + 2 * 32 + ech + j];
                    go += Cs[eb * 128 + 3 * 32 + ech + j];
                    const float cn = fsig(gf) * creg[j] + fsig(gi) * ftanh(gg);
                    creg[j] = cn;
                    hv4[j] = (__bf16)(fsig(go) * ftanh(cn));
                }
                *(bf16x4*)(hout + (size_t)sb * 1024 + ch0 + ech) = hv4;
                if (t == mydl - 1)
                    *(bf16x4*)(sel + (size_t)operm * 1024 + ch0 + ech) = hv4;
            }
        }
        // ---- row-group barrier (ALL blocks, every t) ----
        __threadfence();
        __syncthreads();
        if (tid == 0) {
            atomicAdd(gctr + rg * 16, 1);
            while (atomicAdd(gctr + rg * 16, 0) < 32 * (t + 1))
                __builtin_amdgcn_s_sleep(8);
        }
        __syncthreads();
        __threadfence();
    }
}

// ---- final tiny layer ----
__global__ __launch_bounds__(256) void mlp2(
    const __bf16* __restrict__ y1, const float* __restrict__ W2,
    const float* __restrict__ b2, float* __restrict__ out)
{
    int b = blockIdx.x, tid = threadIdx.x;
    float s0 = 0.f, s1 = 0.f;
    for (int k = tid; k < 1024; k += 256) {
        float v = (float)y1[(size_t)b * 1024 + k];
        s0 += v * W2[k];
        s1 += v * W2[1024 + k];
    }
#pragma unroll
    for (int o = 32; o > 0; o >>= 1) {
        s0 += __shfl_down(s0, o);
        s1 += __shfl_down(s1, o);
    }
    __shared__ float red[8];
    if ((tid & 63) == 0) { red[(tid >> 6) * 2] = s0; red[(tid >> 6) * 2 + 1] = s1; }
    __syncthreads();
    if (tid == 0) {
        float a0 = red[0] + red[2] + red[4] + red[6] + b2[0];
        float a1 = red[1] + red[3] + red[5] + red[7] + b2[1];
        out[b * 2 + 0] = fmaxf(a0, 0.f);
        out[b * 2 + 1] = fmaxf(a1, 0.f);
    }
}

extern "C" void kernel_launch(void* const* d_in, const int* in_sizes, int n_in,
                              void* d_out, int out_size, void* d_ws, size_t ws_size,
                              hipStream_t stream) {
    const int*   ent     = (const int*)d_in[0];
    const int*   rel     = (const int*)d_in[1];
    const int*   dlen    = (const int*)d_in[3];
    const float* ent_emb = (const float*)d_in[4];
    const float* rel_emb = (const float*)d_in[5];
    const float* Wih     = (const float*)d_in[6];
    const float* Whh     = (const float*)d_in[7];
    const float* bih     = (const float*)d_in[8];
    const float* bhh     = (const float*)d_in[9];
    const float* W1      = (const float*)d_in[10];
    const float* b1      = (const float*)d_in[11];
    const float* W2      = (const float*)d_in[12];
    const float* b2      = (const float*)d_in[13];
    float* out = (float*)d_out;

    char* ws = (char*)d_ws;
    size_t off = 0;
    auto alloc = [&](size_t bytes) -> void* {
        void* p = ws + off; off += (bytes + 255) & ~(size_t)255; return p;
    };
    __bf16* xbf    = (__bf16*)alloc(10240UL * 1024 * 2);  // [t*512+sb][1024]
    __bf16* Wih1   = (__bf16*)alloc(4096UL * 1024 * 2);
    __bf16* Whh1   = (__bf16*)alloc(4096UL * 1024 * 2);
    __bf16* W1b    = (__bf16*)alloc(1024UL * 1024 * 2);
    float*  bsum_p = (float*) alloc(4096UL * 4);
    __bf16* Xg     = (__bf16*)alloc(10240UL * 4096 * 2);  // [t*512+sb][ch*4+g]
    __bf16* hA     = (__bf16*)alloc(512UL * 1024 * 2);
    __bf16* hB     = (__bf16*)alloc(512UL * 1024 * 2);
    __bf16* selb   = (__bf16*)alloc(512UL * 1024 * 2);
    __bf16* y1b    = (__bf16*)alloc(512UL * 1024 * 2);
    int*    permb  = (int*)   alloc(512 * 4);
    int*    dl_s   = (int*)   alloc(512 * 4);
    int*    n_act  = (int*)   alloc(32 * 4);
    int*    gctr   = (int*)   alloc(128 * 4);

    sort_rows<<<dim3(1), dim3(512), 0, stream>>>(dlen, permb, dl_s, n_act);
    convert_weights<<<dim3(4096), dim3(256), 0, stream>>>(
        Wih, Whh, W1, bih, bhh, Wih1, Whh1, W1b, bsum_p);
    gather_x<<<dim3(10240), dim3(256), 0, stream>>>(
        ent, rel, ent_emb, rel_emb, permb, xbf);
    // Xg = x @ W_ih[1]^T + (b_ih+b_hh), gate-interleaved cols, dead slabs skipped
    gemm_bias<false, true, true><<<dim3(80, 32), dim3(256), 0, stream>>>(
        xbf, Wih1, bsum_p, Xg, 10240, 4096, 1024, n_act);

    hipMemsetAsync(hA, 0, 512UL * 1024 * 2, stream);
    hipMemsetAsync(hB, 0, 512UL * 1024 * 2, stream);
    hipMemsetAsync(gctr, 0, 128 * 4, stream);

    lstm_all<<<dim3(256), dim3(512), 0, stream>>>(
        Whh1, Xg, hA, hB, selb, dl_s, permb, n_act, gctr);

    gemm_bias<true, false, false><<<dim3(4, 8), dim3(256), 0, stream>>>(
        selb, W1b, b1, y1b, 512, 1024, 1024, nullptr);
    mlp2<<<dim3(512), dim3(256), 0, stream>>>(y1b, W2, b2, out);
}

// Round 6
// 595.134 us; speedup vs baseline: 2.8935x; 2.8525x over previous
//
#include <hip/hip_runtime.h>

typedef __bf16 bf16x8 __attribute__((ext_vector_type(8)));
typedef __bf16 bf16x4 __attribute__((ext_vector_type(4)));
typedef float  f32x4  __attribute__((ext_vector_type(4)));

#define MFMA16 __builtin_amdgcn_mfma_f32_16x16x32_bf16

__device__ __forceinline__ float fsig(float x)  { return 1.f / (1.f + __expf(-x)); }
__device__ __forceinline__ float ftanh(float x) { return 1.f - 2.f / (__expf(2.f * x) + 1.f); }

// B=512, T=20, D=1024, H=1024, 4H=4096. Layer 0 of the LSTM is dead code.
// Rows sorted by dlen descending -> dead work is contiguous -> block early-exit.

// ---- sort batch rows by dlen descending (stable, deterministic) ----
__global__ __launch_bounds__(512) void sort_rows(
    const int* __restrict__ dlen, int* __restrict__ perm,
    int* __restrict__ dl_s, int* __restrict__ n_act)
{
    __shared__ int sdl[512];
    const int b = threadIdx.x;
    const int dl = dlen[b];
    sdl[b] = dl;
    __syncthreads();
    int pos = 0;
    for (int j = 0; j < 512; ++j) {
        const int dj = sdl[j];
        pos += (dj > dl) || (dj == dl && j < b);
    }
    perm[pos] = b;
    dl_s[pos] = dl;
    if (b < 20) {
        int cnt = 0;
        for (int j = 0; j < 512; ++j) cnt += (sdl[j] > b);
        n_act[b] = cnt;           // #rows active at step t (n_act[0]==512)
    }
}

// ---- convert layer-1 weights + W1 to bf16, bsum = b_ih[1]+b_hh[1] ----
__global__ __launch_bounds__(256) void convert_weights(
    const float* __restrict__ Wih, const float* __restrict__ Whh,
    const float* __restrict__ W1,  const float* __restrict__ bih,
    const float* __restrict__ bhh,
    __bf16* __restrict__ Wih1, __bf16* __restrict__ Whh1,
    __bf16* __restrict__ W1b,  float* __restrict__ bsum)
{
    const size_t L1 = 4096UL * 1024UL;
    size_t i = (size_t)blockIdx.x * 256 + threadIdx.x;   // 0 .. 1048575
    float4 a = *(const float4*)(Wih + L1 + i * 4);
    float4 b = *(const float4*)(Whh + L1 + i * 4);
    bf16x4 av = { (__bf16)a.x, (__bf16)a.y, (__bf16)a.z, (__bf16)a.w };
    bf16x4 bv = { (__bf16)b.x, (__bf16)b.y, (__bf16)b.z, (__bf16)b.w };
    *(bf16x4*)(Wih1 + i * 4) = av;
    *(bf16x4*)(Whh1 + i * 4) = bv;
    W1b[i] = (__bf16)W1[i];
    if (i < 4096) bsum[i] = bih[4096 + i] + bhh[4096 + i];
}

// ---- gather x in SORTED row order: xbf[t*512+sb] = [rel_emb | ent_emb] ----
__global__ __launch_bounds__(256) void gather_x(
    const int* __restrict__ ent, const int* __restrict__ rel,
    const float* __restrict__ ent_emb, const float* __restrict__ rel_emb,
    const int* __restrict__ perm, __bf16* __restrict__ xbf)
{
    int bid = blockIdx.x;              // sb*20 + t
    int sb = bid / 20, t = bid - sb * 20;
    int bo = perm[sb];
    int tid = threadIdx.x;
    int col = (tid & 127) * 4;
    const float* src = (tid < 128)
        ? (rel_emb + (size_t)rel[bo * 20 + t] * 512 + col)
        : (ent_emb + (size_t)ent[bo * 20 + t] * 512 + col);
    float4 v = *(const float4*)src;
    bf16x4 o = { (__bf16)v.x, (__bf16)v.y, (__bf16)v.z, (__bf16)v.w };
    int outcol = (tid < 128) ? col : (512 + col);
    *(bf16x4*)(xbf + (size_t)(t * 512 + sb) * 1024 + outcol) = o;
}

// ---- bf16 MFMA GEMM (R1 reg-staged): C = A @ B^T + bias, opt ReLU ----
// SKIP: rows are t-major (row = t*512 + sb, 128 | 512): block dead if
// sb0 >= n_act[t]. 128x128 tile, BK=64, 4 waves.
template<bool RELU, bool SKIP>
__global__ __launch_bounds__(256) void gemm_bias(
    const __bf16* __restrict__ A, const __bf16* __restrict__ B,
    const float* __restrict__ bias, __bf16* __restrict__ C,
    int M, int N, int K, const int* __restrict__ nact)
{
    const int m0 = blockIdx.x * 128, n0 = blockIdx.y * 128;
    if (SKIP) {
        if ((m0 & 511) >= nact[m0 >> 9]) return;
    }
    __shared__ __bf16 As[128 * 64];
    __shared__ __bf16 Bs[128 * 64];
    const int tid = threadIdx.x;
    const int w = tid >> 6, lane = tid & 63;
    const int wr = (w >> 1) * 64, wc = (w & 1) * 64;
    const int srow = w * 32 + (lane >> 3);   // staging row (+j*8)
    const int scol = (lane & 7) * 8;

    f32x4 acc[4][4] = {};
    bf16x8 ar[4], br[4];

#pragma unroll
    for (int j = 0; j < 4; ++j) {
        ar[j] = *(const bf16x8*)(A + (size_t)(m0 + srow + j * 8) * K + scol);
        br[j] = *(const bf16x8*)(B + (size_t)(n0 + srow + j * 8) * K + scol);
    }
    for (int k0 = 0; k0 < K; k0 += 64) {
        __syncthreads();
#pragma unroll
        for (int j = 0; j < 4; ++j) {
            *(bf16x8*)&As[(w * 4 + j) * 512 + lane * 8] = ar[j];
            *(bf16x8*)&Bs[(w * 4 + j) * 512 + lane * 8] = br[j];
        }
        __syncthreads();
        if (k0 + 64 < K) {
#pragma unroll
            for (int j = 0; j < 4; ++j) {
                ar[j] = *(const bf16x8*)(A + (size_t)(m0 + srow + j * 8) * K + k0 + 64 + scol);
                br[j] = *(const bf16x8*)(B + (size_t)(n0 + srow + j * 8) * K + k0 + 64 + scol);
            }
        }
#pragma unroll
        for (int ks = 0; ks < 2; ++ks) {
            const int ko = ks * 32 + (lane >> 4) * 8;
            bf16x8 af[4], bb[4];
#pragma unroll
            for (int i = 0; i < 4; ++i)
                af[i] = *(const bf16x8*)&As[(wr + i * 16 + (lane & 15)) * 64 + ko];
#pragma unroll
            for (int j = 0; j < 4; ++j)
                bb[j] = *(const bf16x8*)&Bs[(wc + j * 16 + (lane & 15)) * 64 + ko];
#pragma unroll
            for (int i = 0; i < 4; ++i)
#pragma unroll
                for (int j = 0; j < 4; ++j)
                    acc[i][j] = MFMA16(af[i], bb[j], acc[i][j], 0, 0, 0);
        }
    }
    const int rbase = m0 + wr + (lane >> 4) * 4;
    const int cbase = n0 + wc + (lane & 15);
#pragma unroll
    for (int j = 0; j < 4; ++j) {
        const int col = cbase + j * 16;
        const float bv = bias[col];
#pragma unroll
        for (int i = 0; i < 4; ++i)
#pragma unroll
            for (int r = 0; r < 4; ++r) {
                float v = acc[i][j][r] + bv;
                if (RELU) v = fmaxf(v, 0.f);
                C[(size_t)(rbase + i * 16 + r) * N + col] = (__bf16)v;
            }
    }
}

// ---- fused recurrent step (R1 structure + skip + sorted rows) ----
// Block: 64 sorted batch rows x (4 gates x 32 channels). Tile col c -> gate
// c>>5, channel j0+(c&31); Whh row (c>>5)*1024 + j0 + (c&31). Each wave:
// 16 rows x 128 cols, so each lane holds gi,gf,gg,go for its (b,ch).
__global__ __launch_bounds__(256) void lstm_step(
    const __bf16* __restrict__ h_in, const __bf16* __restrict__ Whh,
    const __bf16* __restrict__ Xg, float* __restrict__ cst,
    __bf16* __restrict__ h_out, __bf16* __restrict__ sel,
    const int* __restrict__ dl_s, const int* __restrict__ perm,
    const int* __restrict__ n_act, int t)
{
    const int m0 = blockIdx.x * 64;        // sorted batch-row block
    if (m0 >= n_act[t]) return;            // whole slab dead at this step
    __shared__ __bf16 As[64 * 64];
    __shared__ __bf16 Bs[128 * 64];
    const int tid = threadIdx.x;
    const int w = tid >> 6, lane = tid & 63;
    const int j0 = blockIdx.y * 32;        // channel block
    const int scol = (lane & 7) * 8;
    const int arow = w * 16 + (lane >> 3); // A staging row (+j*8)
    const int brow = w * 32 + (lane >> 3); // B staging row (+j*8)

    f32x4 acc[8] = {};
    bf16x8 ar[2], br[4];

#pragma unroll
    for (int j = 0; j < 2; ++j)
        ar[j] = *(const bf16x8*)(h_in + (size_t)(m0 + arow + j * 8) * 1024 + scol);
#pragma unroll
    for (int j = 0; j < 4; ++j) {
        int r = brow + j * 8;
        int R = (r >> 5) * 1024 + j0 + (r & 31);
        br[j] = *(const bf16x8*)(Whh + (size_t)R * 1024 + scol);
    }
    for (int k0 = 0; k0 < 1024; k0 += 64) {
        __syncthreads();
#pragma unroll
        for (int j = 0; j < 2; ++j)
            *(bf16x8*)&As[(w * 2 + j) * 512 + lane * 8] = ar[j];
#pragma unroll
        for (int j = 0; j < 4; ++j)
            *(bf16x8*)&Bs[(w * 4 + j) * 512 + lane * 8] = br[j];
        __syncthreads();
        if (k0 + 64 < 1024) {
#pragma unroll
            for (int j = 0; j < 2; ++j)
                ar[j] = *(const bf16x8*)(h_in + (size_t)(m0 + arow + j * 8) * 1024 + k0 + 64 + scol);
#pragma unroll
            for (int j = 0; j < 4; ++j) {
                int r = brow + j * 8;
                int R = (r >> 5) * 1024 + j0 + (r & 31);
                br[j] = *(const bf16x8*)(Whh + (size_t)R * 1024 + k0 + 64 + scol);
            }
        }
#pragma unroll
        for (int ks = 0; ks < 2; ++ks) {
            const int ko = ks * 32 + (lane >> 4) * 8;
            bf16x8 av = *(const bf16x8*)&As[(w * 16 + (lane & 15)) * 64 + ko];
#pragma unroll
            for (int n = 0; n < 8; ++n) {
                bf16x8 bv = *(const bf16x8*)&Bs[(n * 16 + (lane & 15)) * 64 + ko];
                acc[n] = MFMA16(av, bv, acc[n], 0, 0, 0);
            }
        }
    }
    // epilogue: frag n -> gate n>>1, half n&1; lane col = lane&15
    const int rb = m0 + w * 16 + (lane >> 4) * 4;
#pragma unroll
    for (int half = 0; half < 2; ++half) {
        const int ch = j0 + half * 16 + (lane & 15);
#pragma unroll
        for (int r = 0; r < 4; ++r) {
            const int b = rb + r;          // sorted row index
            const __bf16* xg = Xg + (size_t)(t * 512 + b) * 4096 + ch;
            float gi = acc[0 + half][r] + (float)xg[0];
            float gf = acc[2 + half][r] + (float)xg[1024];
            float gg = acc[4 + half][r] + (float)xg[2048];
            float go = acc[6 + half][r] + (float)xg[3072];
            const size_t ix = (size_t)b * 1024 + ch;
            float cn = fsig(gf) * cst[ix] + fsig(gi) * ftanh(gg);
            cst[ix] = cn;
            float hv = fsig(go) * ftanh(cn);
            h_out[ix] = (__bf16)hv;
            if (dl_s[b] == t + 1)
                sel[(size_t)perm[b] * 1024 + ch] = (__bf16)hv;   // scatter to orig order
        }
    }
}

// ---- final tiny layer: out[b,o] = relu(sum_k y1[b,k]*W2[o,k] + b2[o]) ----
__global__ __launch_bounds__(256) void mlp2(
    const __bf16* __restrict__ y1, const float* __restrict__ W2,
    const float* __restrict__ b2, float* __restrict__ out)
{
    int b = blockIdx.x, tid = threadIdx.x;
    float s0 = 0.f, s1 = 0.f;
    for (int k = tid; k < 1024; k += 256) {
        float v = (float)y1[(size_t)b * 1024 + k];
        s0 += v * W2[k];
        s1 += v * W2[1024 + k];
    }
#pragma unroll
    for (int o = 32; o > 0; o >>= 1) {
        s0 += __shfl_down(s0, o);
        s1 += __shfl_down(s1, o);
    }
    __shared__ float red[8];
    if ((tid & 63) == 0) { red[(tid >> 6) * 2] = s0; red[(tid >> 6) * 2 + 1] = s1; }
    __syncthreads();
    if (tid == 0) {
        float a0 = red[0] + red[2] + red[4] + red[6] + b2[0];
        float a1 = red[1] + red[3] + red[5] + red[7] + b2[1];
        out[b * 2 + 0] = fmaxf(a0, 0.f);
        out[b * 2 + 1] = fmaxf(a1, 0.f);
    }
}

extern "C" void kernel_launch(void* const* d_in, const int* in_sizes, int n_in,
                              void* d_out, int out_size, void* d_ws, size_t ws_size,
                              hipStream_t stream) {
    const int*   ent     = (const int*)d_in[0];
    const int*   rel     = (const int*)d_in[1];
    const int*   dlen    = (const int*)d_in[3];
    const float* ent_emb = (const float*)d_in[4];
    const float* rel_emb = (const float*)d_in[5];
    const float* Wih     = (const float*)d_in[6];
    const float* Whh     = (const float*)d_in[7];
    const float* bih     = (const float*)d_in[8];
    const float* bhh     = (const float*)d_in[9];
    const float* W1      = (const float*)d_in[10];
    const float* b1      = (const float*)d_in[11];
    const float* W2      = (const float*)d_in[12];
    const float* b2      = (const float*)d_in[13];
    float* out = (float*)d_out;

    char* ws = (char*)d_ws;
    size_t off = 0;
    auto alloc = [&](size_t bytes) -> void* {
        void* p = ws + off; off += (bytes + 255) & ~(size_t)255; return p;
    };
    __bf16* xbf   = (__bf16*)alloc(10240UL * 1024 * 2);  // [t*512+sb][1024]
    __bf16* Wih1  = (__bf16*)alloc(4096UL * 1024 * 2);
    __bf16* Whh1  = (__bf16*)alloc(4096UL * 1024 * 2);
    __bf16* W1b   = (__bf16*)alloc(1024UL * 1024 * 2);
    float*  bsum  = (float*) alloc(4096UL * 4);
    __bf16* Xg    = (__bf16*)alloc(10240UL * 4096 * 2);  // [t*512+sb][g*1024+ch]
    __bf16* hA    = (__bf16*)alloc(512UL * 1024 * 2);
    __bf16* hB    = (__bf16*)alloc(512UL * 1024 * 2);
    float*  cst   = (float*) alloc(512UL * 1024 * 4);
    __bf16* selb  = (__bf16*)alloc(512UL * 1024 * 2);    // ORIGINAL row order
    __bf16* y1b   = (__bf16*)alloc(512UL * 1024 * 2);
    int*    permb = (int*)   alloc(512 * 4);
    int*    dl_s  = (int*)   alloc(512 * 4);
    int*    n_act = (int*)   alloc(32 * 4);

    sort_rows<<<dim3(1), dim3(512), 0, stream>>>(dlen, permb, dl_s, n_act);
    convert_weights<<<dim3(4096), dim3(256), 0, stream>>>(
        Wih, Whh, W1, bih, bhh, Wih1, Whh1, W1b, bsum);
    gather_x<<<dim3(10240), dim3(256), 0, stream>>>(
        ent, rel, ent_emb, rel_emb, permb, xbf);
    // Xg = x @ W_ih[1]^T + (b_ih+b_hh); dead 128-row slabs skipped (sorted rows)
    gemm_bias<false, true><<<dim3(80, 32), dim3(256), 0, stream>>>(
        xbf, Wih1, bsum, Xg, 10240, 4096, 1024, n_act);

    hipMemsetAsync(hA, 0, 512UL * 1024 * 2, stream);
    hipMemsetAsync(cst, 0, 512UL * 1024 * 4, stream);

    for (int t = 0; t < 20; ++t) {
        const __bf16* hi = (t & 1) ? hB : hA;
        __bf16*       ho = (t & 1) ? hA : hB;
        lstm_step<<<dim3(8, 32), dim3(256), 0, stream>>>(
            hi, Whh1, Xg, cst, ho, selb, dl_s, permb, n_act, t);
    }

    // y1 = relu(sel @ W1^T + b1)
    gemm_bias<true, false><<<dim3(4, 8), dim3(256), 0, stream>>>(
        selb, W1b, b1, y1b, 512, 1024, 1024, nullptr);
    mlp2<<<dim3(512), dim3(256), 0, stream>>>(y1b, W2, b2, out);
}

// Round 7
// 551.115 us; speedup vs baseline: 3.1246x; 1.0799x over previous
//
#include <hip/hip_runtime.h>

typedef __bf16 bf16x8 __attribute__((ext_vector_type(8)));
typedef __bf16 bf16x4 __attribute__((ext_vector_type(4)));
typedef float  f32x4  __attribute__((ext_vector_type(4)));

#define MFMA16 __builtin_amdgcn_mfma_f32_16x16x32_bf16

__device__ __forceinline__ float fsig(float x)  { return 1.f / (1.f + __expf(-x)); }
__device__ __forceinline__ float ftanh(float x) { return 1.f - 2.f / (__expf(2.f * x) + 1.f); }

// B=512, T=20, D=1024, H=1024, 4H=4096. Layer 0 of the LSTM is dead code.
// Rows sorted by dlen descending -> dead work contiguous -> block early-exit.

// ---- sort batch rows by dlen descending (stable, deterministic) ----
__global__ __launch_bounds__(512) void sort_rows(
    const int* __restrict__ dlen, int* __restrict__ perm,
    int* __restrict__ dl_s, int* __restrict__ n_act)
{
    __shared__ int sdl[512];
    const int b = threadIdx.x;
    const int dl = dlen[b];
    sdl[b] = dl;
    __syncthreads();
    int pos = 0;
    for (int j = 0; j < 512; ++j) {
        const int dj = sdl[j];
        pos += (dj > dl) || (dj == dl && j < b);
    }
    perm[pos] = b;
    dl_s[pos] = dl;
    if (b < 20) {
        int cnt = 0;
        for (int j = 0; j < 512; ++j) cnt += (sdl[j] > b);
        n_act[b] = cnt;           // #rows active at step t (n_act[0]==512)
    }
}

// ---- convert layer-1 weights + W1 to bf16, bsum = b_ih[1]+b_hh[1] ----
__global__ __launch_bounds__(256) void convert_weights(
    const float* __restrict__ Wih, const float* __restrict__ Whh,
    const float* __restrict__ W1,  const float* __restrict__ bih,
    const float* __restrict__ bhh,
    __bf16* __restrict__ Wih1, __bf16* __restrict__ Whh1,
    __bf16* __restrict__ W1b,  float* __restrict__ bsum)
{
    const size_t L1 = 4096UL * 1024UL;
    size_t i = (size_t)blockIdx.x * 256 + threadIdx.x;   // 0 .. 1048575
    float4 a = *(const float4*)(Wih + L1 + i * 4);
    float4 b = *(const float4*)(Whh + L1 + i * 4);
    bf16x4 av = { (__bf16)a.x, (__bf16)a.y, (__bf16)a.z, (__bf16)a.w };
    bf16x4 bv = { (__bf16)b.x, (__bf16)b.y, (__bf16)b.z, (__bf16)b.w };
    *(bf16x4*)(Wih1 + i * 4) = av;
    *(bf16x4*)(Whh1 + i * 4) = bv;
    W1b[i] = (__bf16)W1[i];
    if (i < 4096) bsum[i] = bih[4096 + i] + bhh[4096 + i];
}

// ---- gather x in SORTED row order: xbf[t*512+sb] = [rel_emb | ent_emb] ----
__global__ __launch_bounds__(256) void gather_x(
    const int* __restrict__ ent, const int* __restrict__ rel,
    const float* __restrict__ ent_emb, const float* __restrict__ rel_emb,
    const int* __restrict__ perm, __bf16* __restrict__ xbf)
{
    int bid = blockIdx.x;              // sb*20 + t
    int sb = bid / 20, t = bid - sb * 20;
    int bo = perm[sb];
    int tid = threadIdx.x;
    int col = (tid & 127) * 4;
    const float* src = (tid < 128)
        ? (rel_emb + (size_t)rel[bo * 20 + t] * 512 + col)
        : (ent_emb + (size_t)ent[bo * 20 + t] * 512 + col);
    float4 v = *(const float4*)src;
    bf16x4 o = { (__bf16)v.x, (__bf16)v.y, (__bf16)v.z, (__bf16)v.w };
    int outcol = (tid < 128) ? col : (512 + col);
    *(bf16x4*)(xbf + (size_t)(t * 512 + sb) * 1024 + outcol) = o;
}

// ---- bf16 MFMA GEMM (reg-staged): C = A @ B^T + bias, opt ReLU ----
// SKIP: rows are t-major (row = t*512 + sb): block dead if sb0 >= n_act[t].
template<bool RELU, bool SKIP>
__global__ __launch_bounds__(256) void gemm_bias(
    const __bf16* __restrict__ A, const __bf16* __restrict__ B,
    const float* __restrict__ bias, __bf16* __restrict__ C,
    int M, int N, int K, const int* __restrict__ nact)
{
    const int m0 = blockIdx.x * 128, n0 = blockIdx.y * 128;
    if (SKIP) {
        if ((m0 & 511) >= nact[m0 >> 9]) return;
    }
    __shared__ __bf16 As[128 * 64];
    __shared__ __bf16 Bs[128 * 64];
    const int tid = threadIdx.x;
    const int w = tid >> 6, lane = tid & 63;
    const int wr = (w >> 1) * 64, wc = (w & 1) * 64;
    const int srow = w * 32 + (lane >> 3);   // staging row (+j*8)
    const int scol = (lane & 7) * 8;

    f32x4 acc[4][4] = {};
    bf16x8 ar[4], br[4];

#pragma unroll
    for (int j = 0; j < 4; ++j) {
        ar[j] = *(const bf16x8*)(A + (size_t)(m0 + srow + j * 8) * K + scol);
        br[j] = *(const bf16x8*)(B + (size_t)(n0 + srow + j * 8) * K + scol);
    }
    for (int k0 = 0; k0 < K; k0 += 64) {
        __syncthreads();
#pragma unroll
        for (int j = 0; j < 4; ++j) {
            *(bf16x8*)&As[(w * 4 + j) * 512 + lane * 8] = ar[j];
            *(bf16x8*)&Bs[(w * 4 + j) * 512 + lane * 8] = br[j];
        }
        __syncthreads();
        if (k0 + 64 < K) {
#pragma unroll
            for (int j = 0; j < 4; ++j) {
                ar[j] = *(const bf16x8*)(A + (size_t)(m0 + srow + j * 8) * K + k0 + 64 + scol);
                br[j] = *(const bf16x8*)(B + (size_t)(n0 + srow + j * 8) * K + k0 + 64 + scol);
            }
        }
#pragma unroll
        for (int ks = 0; ks < 2; ++ks) {
            const int ko = ks * 32 + (lane >> 4) * 8;
            bf16x8 af[4], bb[4];
#pragma unroll
            for (int i = 0; i < 4; ++i)
                af[i] = *(const bf16x8*)&As[(wr + i * 16 + (lane & 15)) * 64 + ko];
#pragma unroll
            for (int j = 0; j < 4; ++j)
                bb[j] = *(const bf16x8*)&Bs[(wc + j * 16 + (lane & 15)) * 64 + ko];
#pragma unroll
            for (int i = 0; i < 4; ++i)
#pragma unroll
                for (int j = 0; j < 4; ++j)
                    acc[i][j] = MFMA16(af[i], bb[j], acc[i][j], 0, 0, 0);
        }
    }
    const int rbase = m0 + wr + (lane >> 4) * 4;
    const int cbase = n0 + wc + (lane & 15);
#pragma unroll
    for (int j = 0; j < 4; ++j) {
        const int col = cbase + j * 16;
        const float bv = bias[col];
#pragma unroll
        for (int i = 0; i < 4; ++i)
#pragma unroll
            for (int r = 0; r < 4; ++r) {
                float v = acc[i][j][r] + bv;
                if (RELU) v = fmaxf(v, 0.f);
                C[(size_t)(rbase + i * 16 + r) * N + col] = (__bf16)v;
            }
    }
}

// ---- fused recurrent step v2 ----
// Tile: 32 sorted rows x 256 gate-cols (gate c>>6, channel j0+(c&63)).
// 512 thr / 8 waves: rh=w>>2 (16-row half), cq=w&3 (16-ch quarter); each wave
// 4 frags = the 4 gates at the same (row,ch) -> in-register gate fusion.
// LDS row stride 72 elems (144B): row-to-row bank shift 4 -> <=2-way aliasing
// (free, m136) for both the stride-72 staging writes and the column frag reads.
__global__ __launch_bounds__(512) void lstm_step(
    const __bf16* __restrict__ h_in, const __bf16* __restrict__ Whh,
    const __bf16* __restrict__ Xg, float* __restrict__ cst,
    __bf16* __restrict__ h_out, __bf16* __restrict__ sel,
    const int* __restrict__ dl_s, const int* __restrict__ perm,
    const int* __restrict__ n_act, int t)
{
    const int m0 = blockIdx.x * 32;        // sorted batch-row block
    if (m0 >= n_act[t]) return;            // whole slab dead at this step
    __shared__ __bf16 As[32 * 72];         // 4.5 KB
    __shared__ __bf16 Bs[256 * 72];        // 36 KB
    const int tid = threadIdx.x;
    const int w = tid >> 6, lane = tid & 63;
    const int j0 = blockIdx.y * 64;        // 64-channel block
    const int rh = w >> 2;                 // row half
    const int cq = w & 3;                  // channel quarter

    // staging: thread -> B row (j0+brow) of each gate, 16B piece seg
    const int brow = tid >> 3;             // 0..63
    const int seg  = tid & 7;
    const __bf16* gB = Whh + (size_t)(j0 + brow) * 1024 + seg * 8;
    const __bf16* gA = h_in + (size_t)(m0 + brow) * 1024 + seg * 8;  // tid<256 only (brow<32)

    f32x4 a0 = {0,0,0,0}, a1 = {0,0,0,0}, a2 = {0,0,0,0}, a3 = {0,0,0,0};
    bf16x8 rb0, rb1, rb2, rb3, ra;

    rb0 = *(const bf16x8*)(gB);
    rb1 = *(const bf16x8*)(gB + 1024UL * 1024);
    rb2 = *(const bf16x8*)(gB + 2048UL * 1024);
    rb3 = *(const bf16x8*)(gB + 3072UL * 1024);
    if (tid < 256) ra = *(const bf16x8*)(gA);

    for (int k0 = 0; k0 < 1024; k0 += 64) {
        __syncthreads();
        *(bf16x8*)&Bs[(0 * 64 + brow) * 72 + seg * 8] = rb0;
        *(bf16x8*)&Bs[(1 * 64 + brow) * 72 + seg * 8] = rb1;
        *(bf16x8*)&Bs[(2 * 64 + brow) * 72 + seg * 8] = rb2;
        *(bf16x8*)&Bs[(3 * 64 + brow) * 72 + seg * 8] = rb3;
        if (tid < 256) *(bf16x8*)&As[brow * 72 + seg * 8] = ra;
        __syncthreads();
        if (k0 + 64 < 1024) {
            rb0 = *(const bf16x8*)(gB + k0 + 64);
            rb1 = *(const bf16x8*)(gB + 1024UL * 1024 + k0 + 64);
            rb2 = *(const bf16x8*)(gB + 2048UL * 1024 + k0 + 64);
            rb3 = *(const bf16x8*)(gB + 3072UL * 1024 + k0 + 64);
            if (tid < 256) ra = *(const bf16x8*)(gA + k0 + 64);
        }
#pragma unroll
        for (int ks = 0; ks < 2; ++ks) {
            const int ko = ks * 32 + (lane >> 4) * 8;
            bf16x8 av = *(const bf16x8*)&As[(rh * 16 + (lane & 15)) * 72 + ko];
            bf16x8 b0 = *(const bf16x8*)&Bs[(0 * 64 + cq * 16 + (lane & 15)) * 72 + ko];
            bf16x8 b1 = *(const bf16x8*)&Bs[(1 * 64 + cq * 16 + (lane & 15)) * 72 + ko];
            bf16x8 b2 = *(const bf16x8*)&Bs[(2 * 64 + cq * 16 + (lane & 15)) * 72 + ko];
            bf16x8 b3 = *(const bf16x8*)&Bs[(3 * 64 + cq * 16 + (lane & 15)) * 72 + ko];
            a0 = MFMA16(av, b0, a0, 0, 0, 0);
            a1 = MFMA16(av, b1, a1, 0, 0, 0);
            a2 = MFMA16(av, b2, a2, 0, 0, 0);
            a3 = MFMA16(av, b3, a3, 0, 0, 0);
        }
    }
    // epilogue: lane owns 4 rows x 1 channel, gates = frags a0..a3
    const int ch  = j0 + cq * 16 + (lane & 15);
    const int rb_ = m0 + rh * 16 + (lane >> 4) * 4;
#pragma unroll
    for (int r = 0; r < 4; ++r) {
        const int b = rb_ + r;             // sorted row index
        const __bf16* xg = Xg + (size_t)(t * 512 + b) * 4096 + ch;
        float gi = a0[r] + (float)xg[0];
        float gf = a1[r] + (float)xg[1024];
        float gg = a2[r] + (float)xg[2048];
        float go = a3[r] + (float)xg[3072];
        const size_t ix = (size_t)b * 1024 + ch;
        float cn = fsig(gf) * cst[ix] + fsig(gi) * ftanh(gg);
        cst[ix] = cn;
        float hv = fsig(go) * ftanh(cn);
        h_out[ix] = (__bf16)hv;
        if (dl_s[b] == t + 1)
            sel[(size_t)perm[b] * 1024 + ch] = (__bf16)hv;   // scatter to orig order
    }
}

// ---- final tiny layer: out[b,o] = relu(sum_k y1[b,k]*W2[o,k] + b2[o]) ----
__global__ __launch_bounds__(256) void mlp2(
    const __bf16* __restrict__ y1, const float* __restrict__ W2,
    const float* __restrict__ b2, float* __restrict__ out)
{
    int b = blockIdx.x, tid = threadIdx.x;
    float s0 = 0.f, s1 = 0.f;
    for (int k = tid; k < 1024; k += 256) {
        float v = (float)y1[(size_t)b * 1024 + k];
        s0 += v * W2[k];
        s1 += v * W2[1024 + k];
    }
#pragma unroll
    for (int o = 32; o > 0; o >>= 1) {
        s0 += __shfl_down(s0, o);
        s1 += __shfl_down(s1, o);
    }
    __shared__ float red[8];
    if ((tid & 63) == 0) { red[(tid >> 6) * 2] = s0; red[(tid >> 6) * 2 + 1] = s1; }
    __syncthreads();
    if (tid == 0) {
        float a0 = red[0] + red[2] + red[4] + red[6] + b2[0];
        float a1 = red[1] + red[3] + red[5] + red[7] + b2[1];
        out[b * 2 + 0] = fmaxf(a0, 0.f);
        out[b * 2 + 1] = fmaxf(a1, 0.f);
    }
}

extern "C" void kernel_launch(void* const* d_in, const int* in_sizes, int n_in,
                              void* d_out, int out_size, void* d_ws, size_t ws_size,
                              hipStream_t stream) {
    const int*   ent     = (const int*)d_in[0];
    const int*   rel     = (const int*)d_in[1];
    const int*   dlen    = (const int*)d_in[3];
    const float* ent_emb = (const float*)d_in[4];
    const float* rel_emb = (const float*)d_in[5];
    const float* Wih     = (const float*)d_in[6];
    const float* Whh     = (const float*)d_in[7];
    const float* bih     = (const float*)d_in[8];
    const float* bhh     = (const float*)d_in[9];
    const float* W1      = (const float*)d_in[10];
    const float* b1      = (const float*)d_in[11];
    const float* W2      = (const float*)d_in[12];
    const float* b2      = (const float*)d_in[13];
    float* out = (float*)d_out;

    char* ws = (char*)d_ws;
    size_t off = 0;
    auto alloc = [&](size_t bytes) -> void* {
        void* p = ws + off; off += (bytes + 255) & ~(size_t)255; return p;
    };
    __bf16* xbf   = (__bf16*)alloc(10240UL * 1024 * 2);  // [t*512+sb][1024]
    __bf16* Wih1  = (__bf16*)alloc(4096UL * 1024 * 2);
    __bf16* Whh1  = (__bf16*)alloc(4096UL * 1024 * 2);
    __bf16* W1b   = (__bf16*)alloc(1024UL * 1024 * 2);
    float*  bsum  = (float*) alloc(4096UL * 4);
    __bf16* Xg    = (__bf16*)alloc(10240UL * 4096 * 2);  // [t*512+sb][g*1024+ch]
    __bf16* hA    = (__bf16*)alloc(512UL * 1024 * 2);
    __bf16* hB    = (__bf16*)alloc(512UL * 1024 * 2);
    float*  cst   = (float*) alloc(512UL * 1024 * 4);
    __bf16* selb  = (__bf16*)alloc(512UL * 1024 * 2);    // ORIGINAL row order
    __bf16* y1b   = (__bf16*)alloc(512UL * 1024 * 2);
    int*    permb = (int*)   alloc(512 * 4);
    int*    dl_s  = (int*)   alloc(512 * 4);
    int*    n_act = (int*)   alloc(32 * 4);

    sort_rows<<<dim3(1), dim3(512), 0, stream>>>(dlen, permb, dl_s, n_act);
    convert_weights<<<dim3(4096), dim3(256), 0, stream>>>(
        Wih, Whh, W1, bih, bhh, Wih1, Whh1, W1b, bsum);
    gather_x<<<dim3(10240), dim3(256), 0, stream>>>(
        ent, rel, ent_emb, rel_emb, permb, xbf);
    // Xg = x @ W_ih[1]^T + (b_ih+b_hh); dead 128-row slabs skipped (sorted rows)
    gemm_bias<false, true><<<dim3(80, 32), dim3(256), 0, stream>>>(
        xbf, Wih1, bsum, Xg, 10240, 4096, 1024, n_act);

    hipMemsetAsync(hA, 0, 512UL * 1024 * 2, stream);
    hipMemsetAsync(cst, 0, 512UL * 1024 * 4, stream);

    for (int t = 0; t < 20; ++t) {
        const __bf16* hi = (t & 1) ? hB : hA;
        __bf16*       ho = (t & 1) ? hA : hB;
        lstm_step<<<dim3(16, 16), dim3(512), 0, stream>>>(
            hi, Whh1, Xg, cst, ho, selb, dl_s, permb, n_act, t);
    }

    // y1 = relu(sel @ W1^T + b1)
    gemm_bias<true, false><<<dim3(4, 8), dim3(256), 0, stream>>>(
        selb, W1b, b1, y1b, 512, 1024, 1024, nullptr);
    mlp2<<<dim3(512), dim3(256), 0, stream>>>(y1b, W2, b2, out);
}